// Round 5
// baseline (137.891 us; speedup 1.0000x reference)
//
#include <hip/hip_runtime.h>
#include <cmath>

#pragma clang fp contract(off)

#define NT 1024
constexpr int B_ = 256, Q_ = 300, C_ = 81, V_ = 117, K_ = 100;
constexpr int QC_ = Q_ * C_;   // 24300
constexpr int KV_ = K_ * V_;   // 11700
constexpr int CAP = 1024;      // LDS candidate buffer (fallback sort size)

using u32 = unsigned int;
using u64 = unsigned long long;
using u16 = unsigned short;
using u8  = unsigned char;

// Histogram support: each softmax row max >= 1/81 = 0.0123 (81 values summing
// to 1) -> >= 300 values land in bins >= bin(1/81) = 482, so the top-100
// crossing bin T >= 482. Values below 2^-7 = 0.0078125 (bin 480) can never
// participate. bits >= 0x3C000000 <=> p >= 2^-7 <=> bin >= 480 EXACTLY
// (bin = float-bits >> 21, monotone for positive floats), so a 64-bin
// histogram over [480, 544) gives a bit-identical T.
constexpr u32 PCUT_BITS = 0x3C000000u;
constexpr int BIN0 = 480;
constexpr int NB   = 64;

// ---- LDS layout (lifetime-aliased, hand-packed) ----
constexpr int OFF_HS   = 0;                 // hs f32[11700]=46800 (phase>=6); dead before
constexpr int OFF_HIST = 48600;             // u32[64] | cand u64[1024]=8192 | areas (phase>=5.5)
constexpr int OFF_RMAX = OFF_HIST + 8192;   // f32[300]
constexpr int OFF_RINV = OFF_RMAX + 1200;   // f32[300] per-row 1/sum
constexpr int OFF_BSUB = OFF_RINV + 1208;   // f32[100][4] (16B aligned)
constexpr int OFF_BOBJ = OFF_BSUB + 1600;   // f32[100][4] | wred u64[16] (fallback 5c)
constexpr int OFF_SUPR = OFF_BOBJ + 1600;   // u32[100][4] col-major supmat | s_prev u64 (5c)
constexpr int OFF_SELV = OFF_SUPR + 1600;   // f32[100]
constexpr int OFF_SELI = OFF_SELV + 400;    // u32[100] flat topk index
constexpr int OFF_MAXB = OFF_SELI + 400;    // u32[100] row-max bits
constexpr int OFF_ORD  = OFF_MAXB + 400;    // u8[100] (pad 104)
constexpr int OFF_LAB  = OFF_ORD + 104;     // u8[100] labels (pad 104)
constexpr int OFF_MISC = OFF_LAB + 104;     // skeep[4], keep_bits[4], s_cnt, sT
constexpr int SMEM_SZ  = OFF_MISC + 48;     // 65,456
static_assert(SMEM_SZ <= 65536, "LDS overflow");
static_assert((OFF_BSUB & 15) == 0 && (OFF_BOBJ & 15) == 0, "b128 align");

__device__ __forceinline__ u64 shfl_xor_u64(u64 v, int mask) {
    u32 lo = (u32)v, hi = (u32)(v >> 32);
    lo = (u32)__shfl_xor((int)lo, mask, 64);
    hi = (u32)__shfl_xor((int)hi, mask, 64);
    return ((u64)hi << 32) | lo;
}

// ---- exact butterfly-exchange primitives (same lane pairing as __shfl_xor) --
// xor8 == row_ror:8 (within 16), xor2/xor1 == quad_perm -> VALU DPP (cheap);
// xor16/xor4 stay on ds_swizzle (BitMode (xor<<10)|0x1F).
template <int CTRL>
__device__ __forceinline__ int dpp_i(int x) {
    return __builtin_amdgcn_update_dpp(0, x, CTRL, 0xF, 0xF, true);
}
__device__ __forceinline__ float bfly16(float x){ return __int_as_float(__builtin_amdgcn_ds_swizzle(__float_as_int(x), 0x401F)); }
__device__ __forceinline__ float bfly8 (float x){ return __int_as_float(dpp_i<0x128>(__float_as_int(x))); }
__device__ __forceinline__ float bfly4 (float x){ return __int_as_float(__builtin_amdgcn_ds_swizzle(__float_as_int(x), 0x101F)); }
__device__ __forceinline__ float bfly2 (float x){ return __int_as_float(dpp_i<0x4E>(__float_as_int(x))); }
__device__ __forceinline__ float bfly1 (float x){ return __int_as_float(dpp_i<0xB1>(__float_as_int(x))); }
__device__ __forceinline__ int ibfly4(int x){ return __builtin_amdgcn_ds_swizzle(x, 0x101F); }
__device__ __forceinline__ int ibfly2(int x){ return dpp_i<0x4E>(x); }
__device__ __forceinline__ int ibfly1(int x){ return dpp_i<0xB1>(x); }

// bit-identical to original: inter / ((areaA + areaB) - inter)
__device__ __forceinline__ float iou4(float4 a, float4 b, float areaSum) {
    float xx1 = fmaxf(a.x, b.x);
    float yy1 = fmaxf(a.y, b.y);
    float xx2 = fminf(a.z, b.z);
    float yy2 = fminf(a.w, b.w);
    float w = fmaxf(0.f, xx2 - xx1 + 1.f);
    float h = fmaxf(0.f, yy2 - yy1 + 1.f);
    float inter = w * h;
    return inter / (areaSum - inter);
}

__global__ __launch_bounds__(NT, 4) void hoi_kernel(
    const float* __restrict__ obj_logits,   // B,Q,C
    const float* __restrict__ verb_logits,  // B,Q,V
    const float* __restrict__ sub_boxes_in, // B,Q,4
    const float* __restrict__ obj_boxes_in, // B,Q,4
    const float* __restrict__ cm,           // V,C
    const int*   __restrict__ tsizes,       // B,2 (h,w)
    float* __restrict__ out)
{
    const int b = blockIdx.x;
    const int tid = threadIdx.x;

    __shared__ __align__(16) u8 smem[SMEM_SZ];
    float* hs      = (float*)(smem + OFF_HS);
    u32*   hist    = (u32*)(smem + OFF_HIST);
    u64*   cand    = (u64*)(smem + OFF_HIST);
    float* asub    = (float*)(smem + OFF_HIST);        // phase>=5.5 (hist/cand dead)
    float* aobj    = (float*)(smem + OFF_HIST + 512);  // phase>=5.5
    float* rowmax  = (float*)(smem + OFF_RMAX);
    float* rinv    = (float*)(smem + OFF_RINV);
    float (*bsub)[4]   = (float(*)[4])(smem + OFF_BSUB);
    float (*bobj)[4]   = (float(*)[4])(smem + OFF_BOBJ);
    u32   (*supcol)[4] = (u32(*)[4])(smem + OFF_SUPR); // column-major suppression bits
    float* sel_val = (float*)(smem + OFF_SELV);
    u32*   sel_idx = (u32*)(smem + OFF_SELI);
    u32*   maxbits = (u32*)(smem + OFF_MAXB);
    u8*    order8  = (u8*)(smem + OFF_ORD);
    u8*    lab8    = (u8*)(smem + OFF_LAB);
    u32*   skeep     = (u32*)(smem + OFF_MISC);
    u32*   keep_bits = (u32*)(smem + OFF_MISC + 16);
    u32*   s_cnt     = (u32*)(smem + OFF_MISC + 32);
    int*   sT        = (int*)(smem + OFF_MISC + 36);
    u64*   wred    = (u64*)(smem + OFF_BOBJ);   // 5c scratch
    u64*   s_prev  = (u64*)(smem + OFF_SUPR);   // 5c scratch

    const float* lg = obj_logits + (size_t)b * QC_;

    if (tid < NB) hist[tid] = 0;
    if (tid == 0) *s_cnt = 0;
    __syncthreads();

    // ---- Phase 1 (fused): softmax + histogram. Cross-barrier state is ONE
    // u32 candidate mask per thread (bit 3s+c = element of row-slot s, col c
    // has p >= 2^-7). Probabilities are NOT kept live (round-4 lesson: the
    // allocator spills them, adding ~30us of stall); phase 4 recomputes the
    // ~2 masked elements per thread bit-identically from lg/rowmax/rinv.
    // TEN rows per 32-lane group: all 30 loads up front, 10 interleaved
    // butterfly chains (xor8/2/1 via DPP, xor16/4 via ds_swizzle). Exact
    // same element order + reduce pairing as before -> bit-identical.
    const int g = tid >> 5, l = tid & 31;
    const bool have2 = (l < C_ - 64);   // l < 17
    u32 cmask = 0;
    {
        float v0[10], v1[10], v2[10];
        #pragma unroll
        for (int s = 0; s < 10; ++s) {
            int r = g + 32 * s;
            const float* row = lg + (size_t)((r < Q_ ? r : Q_ - 1) * C_);
            v0[s] = row[l];
            v1[s] = row[l + 32];
            v2[s] = have2 ? row[l + 64] : -INFINITY;
        }
        float m[10];
        #pragma unroll
        for (int s = 0; s < 10; ++s) m[s] = fmaxf(fmaxf(v0[s], v1[s]), v2[s]);
        #pragma unroll
        for (int s = 0; s < 10; ++s) m[s] = fmaxf(m[s], bfly16(m[s]));
        #pragma unroll
        for (int s = 0; s < 10; ++s) m[s] = fmaxf(m[s], bfly8(m[s]));
        #pragma unroll
        for (int s = 0; s < 10; ++s) m[s] = fmaxf(m[s], bfly4(m[s]));
        #pragma unroll
        for (int s = 0; s < 10; ++s) m[s] = fmaxf(m[s], bfly2(m[s]));
        #pragma unroll
        for (int s = 0; s < 10; ++s) m[s] = fmaxf(m[s], bfly1(m[s]));
        float e0[10], e1[10], e2[10], sm[10];
        #pragma unroll
        for (int s = 0; s < 10; ++s) {
            e0[s] = expf(v0[s] - m[s]);
            e1[s] = expf(v1[s] - m[s]);
            e2[s] = have2 ? expf(v2[s] - m[s]) : 0.f;
            sm[s] = e0[s] + e1[s] + e2[s];
        }
        #pragma unroll
        for (int s = 0; s < 10; ++s) sm[s] += bfly16(sm[s]);
        #pragma unroll
        for (int s = 0; s < 10; ++s) sm[s] += bfly8(sm[s]);
        #pragma unroll
        for (int s = 0; s < 10; ++s) sm[s] += bfly4(sm[s]);
        #pragma unroll
        for (int s = 0; s < 10; ++s) sm[s] += bfly2(sm[s]);
        #pragma unroll
        for (int s = 0; s < 10; ++s) sm[s] += bfly1(sm[s]);
        #pragma unroll
        for (int s = 0; s < 10; ++s) {
            int r = g + 32 * s;
            if (r < Q_) {
                float ri = 1.f / sm[s];
                float p0 = e0[s] * ri, p1 = e1[s] * ri;
                u32 x0 = __float_as_uint(p0), x1 = __float_as_uint(p1);
                if (x0 >= PCUT_BITS) {
                    atomicAdd(&hist[(x0 >> 21) - BIN0], 1u);
                    cmask |= 1u << (3 * s);
                }
                if (x1 >= PCUT_BITS) {
                    atomicAdd(&hist[(x1 >> 21) - BIN0], 1u);
                    cmask |= 1u << (3 * s + 1);
                }
                if (have2) {
                    float p2 = e2[s] * ri;
                    u32 x2 = __float_as_uint(p2);
                    if (x2 >= PCUT_BITS) {
                        atomicAdd(&hist[(x2 >> 21) - BIN0], 1u);
                        cmask |= 1u << (3 * s + 2);
                    }
                }
                if (l == 0) { rowmax[r] = m[s]; rinv[r] = ri; }
            }
        }
    }
    __syncthreads();

    // ---- Phase 3: threshold bin T — single-wave 64-bin suffix scan ----
    if (tid < 64) {
        u32 suf = hist[tid];
        #pragma unroll
        for (int off = 1; off < 64; off <<= 1) {
            u32 o = (u32)__shfl_down((int)suf, off, 64);
            suf += (tid + off < 64) ? o : 0;
        }
        u32 nxt = (u32)__shfl_down((int)suf, 1, 64);
        if (tid == 63) nxt = 0;
        if (suf >= (u32)K_ && nxt < (u32)K_) *sT = BIN0 + tid;
    }
    __syncthreads();   // T visible; hist dead (cand may alias)
    const int T = *sT;

    // ---- Phase 4: candidate scan driven by the mask — recompute prob for
    // the ~2 masked elements per thread, bit-identical to phase 1
    // (same expf(v-m)*ri with the exact same m, ri values from LDS). ----
    u32 mk = cmask;
    while (mk) {
        int bpos = (int)__builtin_ctz(mk);
        mk &= mk - 1;
        int s = (bpos * 171) >> 9;       // floor(bpos/3) for bpos in [0,30)
        int c = bpos - 3 * s;
        int r = g + 32 * s;
        int col = l + 32 * c;
        int i = r * C_ + col;
        float p = expf(lg[i] - rowmax[r]) * rinv[r];
        u32 xb = __float_as_uint(p);
        if ((int)(xb >> 21) >= T) {
            u32 pos = atomicAdd(s_cnt, 1u);
            if (pos < (u32)CAP)
                cand[pos] = ((u64)xb << 32) | (u32)(~i);
        }
    }
    __syncthreads();
    const int ncand = (int)*s_cnt;

    auto cswap = [](u64& a, u64& bb, bool up) {
        if ((a > bb) == up) { u64 t = a; a = bb; bb = t; }
    };

    if (ncand <= 256) {
        // ---- Phase 5a: register-resident bitonic-256 on wave 0 — zero barriers ----
        if (tid < 64) {
            u64 v0 = (tid < ncand) ? cand[tid] : 0ull;
            u64 v1 = (64 + tid < ncand) ? cand[64 + tid] : 0ull;
            u64 v2 = (128 + tid < ncand) ? cand[128 + tid] : 0ull;
            u64 v3 = (192 + tid < ncand) ? cand[192 + tid] : 0ull;
            for (int k = 2; k <= 256; k <<= 1) {
                for (int j = k >> 1; j > 0; j >>= 1) {
                    if (j == 128) {
                        cswap(v0, v2, true);
                        cswap(v1, v3, true);
                    } else if (j == 64) {
                        cswap(v0, v1, true);
                        cswap(v2, v3, (k == 256));
                    } else {
                        auto step = [&](u64& v, int ebase) {
                            u64 pv = shfl_xor_u64(v, j);
                            int e = ebase + tid;
                            bool up = ((e & k) == 0);
                            bool lower = ((e & j) == 0);
                            u64 mn = v < pv ? v : pv;
                            u64 mx = v < pv ? pv : v;
                            v = (lower == up) ? mn : mx;
                        };
                        step(v0, 0); step(v1, 64); step(v2, 128); step(v3, 192);
                    }
                }
            }
            int e2 = 128 + tid;
            if (e2 >= 156) {
                int t = 255 - e2;
                sel_val[t] = __uint_as_float((u32)(v2 >> 32));
                sel_idx[t] = ~(u32)v2;
            }
            int t3 = 255 - (192 + tid);
            sel_val[t3] = __uint_as_float((u32)(v3 >> 32));
            sel_idx[t3] = ~(u32)v3;
        }
    } else if (ncand <= CAP) {
        // ---- Phase 5b: LDS bitonic-1024 fallback ----
        for (int e = tid; e < CAP; e += NT)
            if (e >= ncand) cand[e] = 0;
        __syncthreads();
        for (int k = 2; k <= CAP; k <<= 1) {
            for (int j = k >> 1; j > 0; j >>= 1) {
                int e = tid, partner = e ^ j;
                if (partner > e) {
                    u64 a = cand[e], bb = cand[partner];
                    bool up = ((e & k) == 0);
                    if ((a > bb) == up) { cand[e] = bb; cand[partner] = a; }
                }
                __syncthreads();
            }
        }
        if (tid < K_) {
            u64 m = cand[CAP - 1 - tid];
            sel_val[tid] = __uint_as_float((u32)(m >> 32));
            sel_idx[tid] = ~(u32)m;
        }
    } else {
        // ---- Phase 5c (near-dead): 100-round argmax with strict-less chaining ----
        if (tid == 0) *s_prev = ~0ull;
        __syncthreads();
        for (int r = 0; r < K_; r++) {
            u64 prev = *s_prev;
            u64 local = 0;
            for (int i = tid; i < QC_; i += NT) {
                int q = i / C_;
                float p = expf(lg[i] - rowmax[q]) * rinv[q];
                u64 key = ((u64)__float_as_uint(p) << 32) | (u32)(~i);
                if (key < prev && key > local) local = key;
            }
            for (int off = 32; off > 0; off >>= 1) {
                u64 o = shfl_xor_u64(local, off);
                if (o > local) local = o;
            }
            if ((tid & 63) == 0) wred[tid >> 6] = local;
            __syncthreads();
            if (tid == 0) {
                u64 m = wred[0];
                for (int wv = 1; wv < 16; wv++) if (wred[wv] > m) m = wred[wv];
                *s_prev = m;
                u32 idx = ~(u32)m;
                if (idx >= (u32)QC_) idx = 0;
                sel_val[r] = __uint_as_float((u32)(m >> 32));
                sel_idx[r] = idx;
            }
            __syncthreads();
        }
    }
    __syncthreads();   // sel_* visible; hist/cand/rowstats dead

    // ---- Fused phase 5.5+6+6.5: threads 0-799 compute hoi scores row-per-
    // 8-lane-cluster with in-register row max; threads 800-999 do box
    // gather+scale+areas; 1000-1003 zero keep_bits. ----
    if (tid < 800) {
        int c = tid >> 3, j = tid & 7;
        u32 idx = sel_idx[c];
        int q = (int)idx / C_, lab = (int)idx - q * C_;
        const float* vrow = verb_logits + ((size_t)b * Q_ + q) * V_;
        float sv = sel_val[c];
        float xv[15], cv[15];
        #pragma unroll
        for (int k = 0; k < 15; ++k) {
            int v = j + 8 * k;
            int vc = v < V_ ? v : V_ - 1;
            xv[k] = vrow[vc];
            cv[k] = cm[vc * C_ + lab];
        }
        float m = 0.f;   // hvals >= 0
        #pragma unroll
        for (int k = 0; k < 15; ++k) {
            int v = j + 8 * k;
            if (v < V_) {
                float hv = (1.f / (1.f + expf(-xv[k]))) * sv * cv[k];
                hs[c * V_ + v] = hv;
                m = fmaxf(m, hv);
            }
        }
        m = fmaxf(m, bfly4(m));
        m = fmaxf(m, bfly2(m));
        m = fmaxf(m, bfly1(m));
        if (j == 0) { maxbits[c] = __float_as_uint(m); lab8[c] = (u8)lab; }
    } else if (tid < 900) {
        int t = tid - 800;
        int idx = (int)sel_idx[t];
        int q = idx / C_;
        float iw = (float)tsizes[b * 2 + 1];
        float ih = (float)tsizes[b * 2 + 0];
        float4 sb = ((const float4*)sub_boxes_in)[(size_t)b * Q_ + q];
        float x1 = (sb.x - 0.5f * sb.z) * iw, y1 = (sb.y - 0.5f * sb.w) * ih;
        float x2 = (sb.x + 0.5f * sb.z) * iw, y2 = (sb.y + 0.5f * sb.w) * ih;
        bsub[t][0] = x1; bsub[t][1] = y1; bsub[t][2] = x2; bsub[t][3] = y2;
        asub[t] = (x2 - x1 + 1.f) * (y2 - y1 + 1.f);
        supcol[t][0] = 0; supcol[t][1] = 0; supcol[t][2] = 0; supcol[t][3] = 0;
    } else if (tid < 1000) {
        int t = tid - 900;
        int idx = (int)sel_idx[t];
        int q = idx / C_;
        float iw = (float)tsizes[b * 2 + 1];
        float ih = (float)tsizes[b * 2 + 0];
        float4 ob = ((const float4*)obj_boxes_in)[(size_t)b * Q_ + q];
        float x1 = (ob.x - 0.5f * ob.z) * iw, y1 = (ob.y - 0.5f * ob.w) * ih;
        float x2 = (ob.x + 0.5f * ob.z) * iw, y2 = (ob.y + 0.5f * ob.w) * ih;
        bobj[t][0] = x1; bobj[t][1] = y1; bobj[t][2] = x2; bobj[t][3] = y2;
        aobj[t] = (x2 - x1 + 1.f) * (y2 - y1 + 1.f);
    } else if (tid < 1004) {
        keep_bits[tid - 1000] = 0;
    }
    __syncthreads();

    // ---- Phase 7: stable descending rank, 8 lanes/row, exact int sums ----
    if (tid < 800) {
        int r = tid >> 3, j = tid & 7;
        u64 kr = ((u64)maxbits[r] << 32) | (u32)(~r);
        int rank = 0;
        for (int k = 0; k < 13; k++) {
            int jj = j * 13 + k;
            if (jj < K_) {
                u64 kj = ((u64)maxbits[jj] << 32) | (u32)(~jj);
                rank += (kj > kr) ? 1 : 0;
            }
        }
        rank += ibfly4(rank);
        rank += ibfly2(rank);
        rank += ibfly1(rank);
        if (j == 0) order8[rank] = (u8)r;
    }
    __syncthreads();

    // ---- Early output writes: o1..o4 depend only on sel/boxes (NOT keep).
    // Issue them here so the global stores drain underneath phases 8a/8b. ----
    float* o0 = out;                                   // final_scores B,K,V
    float* o1 = out + (size_t)B_ * KV_;                // topk_values  B,K
    float* o2 = o1 + (size_t)B_ * K_;                  // obj_labels   B,K
    float* o3 = o2 + (size_t)B_ * K_;                  // sub_boxes    B,K,4
    float* o4 = o3 + (size_t)B_ * K_ * 4;              // obj_boxes    B,K,4
    float* o5 = o4 + (size_t)B_ * K_ * 4;              // keep         B,K

    if (tid < K_) {
        o1[(size_t)b * K_ + tid] = sel_val[tid];
        o2[(size_t)b * K_ + tid] = (float)(sel_idx[tid] % (u32)C_);
    }
    if (tid >= 128 && tid < 128 + K_ * 4) {
        int t = tid - 128;
        int r = t >> 2, k = t & 3;
        o3[((size_t)b * K_) * 4 + t] = bsub[r][k];
        o4[((size_t)b * K_) * 4 + t] = bobj[r][k];
    }

    // ---- Phase 8a: 100x100 suppression bitmatrix, COLUMN-major in sorted
    // space (b128 box loads + precomputed areas + cached labels) ----
    for (int e = tid; e < K_ * K_; e += NT) {
        int i = e / K_, j = e - i * K_;
        if (j > i) {
            int ri = order8[i], rj = order8[j];
            u32 li = lab8[ri], lj = lab8[rj];
            if (li == lj) {
                float4 s_i = *(const float4*)bsub[ri];
                float4 s_j = *(const float4*)bsub[rj];
                float4 b_i = *(const float4*)bobj[ri];
                float4 b_j = *(const float4*)bobj[rj];
                float o = iou4(s_i, s_j, asub[ri] + asub[rj]) *
                          iou4(b_i, b_j, aobj[ri] + aobj[rj]);
                if (o > 0.5f)
                    atomicOr(&supcol[j][i >> 5], 1u << (i & 31));
            }
        }
    }
    __syncthreads();

    // ---- Phase 8b: greedy scan via ballot — lane j owns column j's
    // suppressed flag; sup_i read from the ballot mask (scalar), updates are
    // 2 VALU ops. No cross-lane shuffles at all. ----
    if (tid < 64) {
        u32 cA[4], cB[4];
        #pragma unroll
        for (int w = 0; w < 4; ++w) cA[w] = supcol[tid][w];
        #pragma unroll
        for (int w = 0; w < 4; ++w) cB[w] = (tid < K_ - 64) ? supcol[tid + 64][w] : 0u;
        bool sA = false, sB = false;
        u32 km[4] = {0, 0, 0, 0};
        #pragma unroll
        for (int i = 0; i < 64; ++i) {
            u64 bal = __ballot(sA);
            if (!((bal >> i) & 1)) {          // uniform branch
                km[i >> 5] |= 1u << (i & 31);
                sA = sA || ((cA[i >> 5] >> (i & 31)) & 1u);
                sB = sB || ((cB[i >> 5] >> (i & 31)) & 1u);
            }
        }
        #pragma unroll
        for (int i = 64; i < K_; ++i) {
            u64 bal = __ballot(sB);
            if (!((bal >> (i - 64)) & 1)) {   // uniform branch
                km[i >> 5] |= 1u << (i & 31);
                sA = sA || ((cA[i >> 5] >> (i & 31)) & 1u);
                sB = sB || ((cB[i >> 5] >> (i & 31)) & 1u);
            }
        }
        if (tid == 0) { skeep[0] = km[0]; skeep[1] = km[1]; skeep[2] = km[2]; skeep[3] = km[3]; }
    }
    __syncthreads();
    if (tid < K_) {
        if ((skeep[tid >> 5] >> (tid & 31)) & 1u) {
            int r = order8[tid];
            atomicOr(&keep_bits[r >> 5], 1u << (r & 31));
        }
    }
    __syncthreads();

    // ---- Phase 9: write remaining outputs (o0 final_scores, o5 keep) ----
    // final_scores as float4: 11700/4 = 2925 vecs, 16B-aligned both sides.
    constexpr int KV4_ = KV_ / 4;
    for (int f4 = tid; f4 < KV4_; f4 += NT) {
        int base = f4 * 4;
        float4 h = *(const float4*)(hs + base);
        int r0 = base / V_, m0 = base - r0 * V_;
        int r1 = r0 + ((m0 + 1) >= V_ ? 1 : 0);
        int r2 = r0 + ((m0 + 2) >= V_ ? 1 : 0);
        int r3 = r0 + ((m0 + 3) >= V_ ? 1 : 0);
        float4 o;
        o.x = ((keep_bits[r0 >> 5] >> (r0 & 31)) & 1u) ? h.x : 0.f;
        o.y = ((keep_bits[r1 >> 5] >> (r1 & 31)) & 1u) ? h.y : 0.f;
        o.z = ((keep_bits[r2 >> 5] >> (r2 & 31)) & 1u) ? h.z : 0.f;
        o.w = ((keep_bits[r3 >> 5] >> (r3 & 31)) & 1u) ? h.w : 0.f;
        *(float4*)(o0 + (size_t)b * KV_ + base) = o;
    }
    if (tid < K_) {
        bool kp = (keep_bits[tid >> 5] >> (tid & 31)) & 1u;
        o5[(size_t)b * K_ + tid] = kp ? 1.f : 0.f;
    }
}

extern "C" void kernel_launch(void* const* d_in, const int* in_sizes, int n_in,
                              void* d_out, int out_size, void* d_ws, size_t ws_size,
                              hipStream_t stream) {
    const float* obj_logits  = (const float*)d_in[0];
    const float* verb_logits = (const float*)d_in[1];
    const float* sub_boxes   = (const float*)d_in[2];
    const float* obj_boxes   = (const float*)d_in[3];
    const float* cm          = (const float*)d_in[4];
    const int*   ts          = (const int*)d_in[5];
    hipLaunchKernelGGL(hoi_kernel, dim3(B_), dim3(NT), 0, stream,
                       obj_logits, verb_logits, sub_boxes, obj_boxes, cm, ts,
                       (float*)d_out);
}

// Round 7
// 129.609 us; speedup vs baseline: 1.0639x; 1.0639x over previous
//
#include <hip/hip_runtime.h>
#include <cmath>

#pragma clang fp contract(off)

#define NT 1024
constexpr int B_ = 256, Q_ = 300, C_ = 81, V_ = 117, K_ = 100;
constexpr int QC_ = Q_ * C_;   // 24300
constexpr int KV_ = K_ * V_;   // 11700
constexpr int CAP = 1024;      // LDS candidate buffer (fallback sort size)

using u32 = unsigned int;
using u64 = unsigned long long;
using u16 = unsigned short;
using u8  = unsigned char;

// Histogram support: each softmax row max >= 1/81 = 0.0123 (81 values summing
// to 1) -> >= 300 values land in bins >= bin(1/81) = 482, so the top-100
// crossing bin T >= 482. Values below 2^-7 = 0.0078125 (bin 480) can never
// participate. bits >= 0x3C000000 <=> p >= 2^-7 <=> bin >= 480 EXACTLY
// (bin = float-bits >> 21, monotone for positive floats), so a 64-bin
// histogram over [480, 544) gives a bit-identical T.
constexpr u32 PCUT_BITS = 0x3C000000u;
constexpr int BIN0 = 480;
constexpr int NB   = 64;

// ---- LDS layout (lifetime-aliased, hand-packed; 63,744 B) ----
constexpr int OFF_HS   = 0;                 // hs f32[11700]=46800 (phase>=6); dead before
constexpr int OFF_HIST = 46816;             // u32[64] | cand u64[1024]=8192 | areas (phase>=5.5)
constexpr int OFF_RMAX = OFF_HIST + 8192;   // f32[309] PADDED: idx r+(r>>5) -> bank (g+s)%32
constexpr int OFF_RINV = OFF_RMAX + 1240;   // f32[309] padded likewise
constexpr int OFF_BSUB = OFF_RINV + 1240;   // f32[100][4] (16B aligned)
constexpr int OFF_BOBJ = OFF_BSUB + 1600;   // f32[100][4] | wred u64[16] (fallback 5c)
constexpr int OFF_SUPR = OFF_BOBJ + 1600;   // u32[100][4] col-major supmat | s_prev u64 (5c)
constexpr int OFF_SELV = OFF_SUPR + 1600;   // f32[100]
constexpr int OFF_SELI = OFF_SELV + 400;    // u32[100] flat topk index
constexpr int OFF_MAXB = OFF_SELI + 400;    // u32[100] row-max bits
constexpr int OFF_ORD  = OFF_MAXB + 400;    // u8[100] (pad 104)
constexpr int OFF_LAB  = OFF_ORD + 104;     // u8[100] labels (pad 104)
constexpr int OFF_MISC = OFF_LAB + 104;     // skeep[4], keep_bits[4], s_cnt, sT
constexpr int SMEM_SZ  = OFF_MISC + 48;     // 63,744
static_assert(SMEM_SZ <= 65536, "LDS overflow");
static_assert((OFF_BSUB & 15) == 0 && (OFF_BOBJ & 15) == 0, "b128 align");
static_assert(OFF_HIST >= 46800, "cand/hs overlap");

// padded row-stat index: r + r/32 -> consecutive s-steps (r += 32) move by 33
// slots = different LDS bank each step (fixes the 32-way conflict of r5).
__device__ __forceinline__ int RM(int r) { return r + (r >> 5); }

__device__ __forceinline__ u64 shfl_xor_u64(u64 v, int mask) {
    u32 lo = (u32)v, hi = (u32)(v >> 32);
    lo = (u32)__shfl_xor((int)lo, mask, 64);
    hi = (u32)__shfl_xor((int)hi, mask, 64);
    return ((u64)hi << 32) | lo;
}

// ---- exact butterfly-exchange primitives (same lane pairing as __shfl_xor) --
// xor8 == row_ror:8 (within 16), xor2/xor1 == quad_perm -> VALU DPP (cheap);
// xor16/xor4 stay on ds_swizzle (BitMode (xor<<10)|0x1F).
template <int CTRL>
__device__ __forceinline__ int dpp_i(int x) {
    return __builtin_amdgcn_update_dpp(0, x, CTRL, 0xF, 0xF, true);
}
__device__ __forceinline__ float bfly16(float x){ return __int_as_float(__builtin_amdgcn_ds_swizzle(__float_as_int(x), 0x401F)); }
__device__ __forceinline__ float bfly8 (float x){ return __int_as_float(dpp_i<0x128>(__float_as_int(x))); }
__device__ __forceinline__ float bfly4 (float x){ return __int_as_float(__builtin_amdgcn_ds_swizzle(__float_as_int(x), 0x101F)); }
__device__ __forceinline__ float bfly2 (float x){ return __int_as_float(dpp_i<0x4E>(__float_as_int(x))); }
__device__ __forceinline__ float bfly1 (float x){ return __int_as_float(dpp_i<0xB1>(__float_as_int(x))); }
__device__ __forceinline__ int ibfly4(int x){ return __builtin_amdgcn_ds_swizzle(x, 0x101F); }
__device__ __forceinline__ int ibfly2(int x){ return dpp_i<0x4E>(x); }
__device__ __forceinline__ int ibfly1(int x){ return dpp_i<0xB1>(x); }

// bit-identical to original: inter / ((areaA + areaB) - inter)
__device__ __forceinline__ float iou4(float4 a, float4 b, float areaSum) {
    float xx1 = fmaxf(a.x, b.x);
    float yy1 = fmaxf(a.y, b.y);
    float xx2 = fminf(a.z, b.z);
    float yy2 = fminf(a.w, b.w);
    float w = fmaxf(0.f, xx2 - xx1 + 1.f);
    float h = fmaxf(0.f, yy2 - yy1 + 1.f);
    float inter = w * h;
    return inter / (areaSum - inter);
}

__global__ __launch_bounds__(NT, 4) void hoi_kernel(
    const float* __restrict__ obj_logits,   // B,Q,C
    const float* __restrict__ verb_logits,  // B,Q,V
    const float* __restrict__ sub_boxes_in, // B,Q,4
    const float* __restrict__ obj_boxes_in, // B,Q,4
    const float* __restrict__ cm,           // V,C
    const int*   __restrict__ tsizes,       // B,2 (h,w)
    float* __restrict__ out)
{
    const int b = blockIdx.x;
    const int tid = threadIdx.x;

    __shared__ __align__(16) u8 smem[SMEM_SZ];
    float* hs      = (float*)(smem + OFF_HS);
    u32*   hist    = (u32*)(smem + OFF_HIST);
    u64*   cand    = (u64*)(smem + OFF_HIST);
    float* asub    = (float*)(smem + OFF_HIST);        // phase>=5.5 (hist/cand dead)
    float* aobj    = (float*)(smem + OFF_HIST + 512);  // phase>=5.5
    float* rowmax  = (float*)(smem + OFF_RMAX);
    float* rinv    = (float*)(smem + OFF_RINV);
    float (*bsub)[4]   = (float(*)[4])(smem + OFF_BSUB);
    float (*bobj)[4]   = (float(*)[4])(smem + OFF_BOBJ);
    u32   (*supcol)[4] = (u32(*)[4])(smem + OFF_SUPR); // column-major suppression bits
    float* sel_val = (float*)(smem + OFF_SELV);
    u32*   sel_idx = (u32*)(smem + OFF_SELI);
    u32*   maxbits = (u32*)(smem + OFF_MAXB);
    u8*    order8  = (u8*)(smem + OFF_ORD);
    u8*    lab8    = (u8*)(smem + OFF_LAB);
    u32*   skeep     = (u32*)(smem + OFF_MISC);
    u32*   keep_bits = (u32*)(smem + OFF_MISC + 16);
    u32*   s_cnt     = (u32*)(smem + OFF_MISC + 32);
    int*   sT        = (int*)(smem + OFF_MISC + 36);
    u64*   wred    = (u64*)(smem + OFF_BOBJ);   // 5c scratch
    u64*   s_prev  = (u64*)(smem + OFF_SUPR);   // 5c scratch

    const float* lg = obj_logits + (size_t)b * QC_;

    if (tid < NB) hist[tid] = 0;
    if (tid == 0) *s_cnt = 0;
    __syncthreads();

    // ---- Phase 1 (fused): softmax + histogram. Cross-barrier state is ONE
    // u32 candidate mask per thread (bit 3s+c = element of row-slot s, col c
    // has p >= 2^-7). Probabilities are NOT kept live (round-4 lesson: the
    // allocator spills them); phase 4 recomputes the ~2 masked elements per
    // thread bit-identically from lg/rowmax/rinv.
    const int g = tid >> 5, l = tid & 31;
    const bool have2 = (l < C_ - 64);   // l < 17
    u32 cmask = 0;
    {
        float v0[10], v1[10], v2[10];
        #pragma unroll
        for (int s = 0; s < 10; ++s) {
            int r = g + 32 * s;
            const float* row = lg + (size_t)((r < Q_ ? r : Q_ - 1) * C_);
            v0[s] = row[l];
            v1[s] = row[l + 32];
            v2[s] = have2 ? row[l + 64] : -INFINITY;
        }
        float m[10];
        #pragma unroll
        for (int s = 0; s < 10; ++s) m[s] = fmaxf(fmaxf(v0[s], v1[s]), v2[s]);
        #pragma unroll
        for (int s = 0; s < 10; ++s) m[s] = fmaxf(m[s], bfly16(m[s]));
        #pragma unroll
        for (int s = 0; s < 10; ++s) m[s] = fmaxf(m[s], bfly8(m[s]));
        #pragma unroll
        for (int s = 0; s < 10; ++s) m[s] = fmaxf(m[s], bfly4(m[s]));
        #pragma unroll
        for (int s = 0; s < 10; ++s) m[s] = fmaxf(m[s], bfly2(m[s]));
        #pragma unroll
        for (int s = 0; s < 10; ++s) m[s] = fmaxf(m[s], bfly1(m[s]));
        float e0[10], e1[10], e2[10], sm[10];
        #pragma unroll
        for (int s = 0; s < 10; ++s) {
            e0[s] = expf(v0[s] - m[s]);
            e1[s] = expf(v1[s] - m[s]);
            e2[s] = have2 ? expf(v2[s] - m[s]) : 0.f;
            sm[s] = e0[s] + e1[s] + e2[s];
        }
        #pragma unroll
        for (int s = 0; s < 10; ++s) sm[s] += bfly16(sm[s]);
        #pragma unroll
        for (int s = 0; s < 10; ++s) sm[s] += bfly8(sm[s]);
        #pragma unroll
        for (int s = 0; s < 10; ++s) sm[s] += bfly4(sm[s]);
        #pragma unroll
        for (int s = 0; s < 10; ++s) sm[s] += bfly2(sm[s]);
        #pragma unroll
        for (int s = 0; s < 10; ++s) sm[s] += bfly1(sm[s]);
        #pragma unroll
        for (int s = 0; s < 10; ++s) {
            int r = g + 32 * s;
            if (r < Q_) {
                float ri = 1.f / sm[s];
                float p0 = e0[s] * ri, p1 = e1[s] * ri;
                u32 x0 = __float_as_uint(p0), x1 = __float_as_uint(p1);
                if (x0 >= PCUT_BITS) {
                    atomicAdd(&hist[(x0 >> 21) - BIN0], 1u);
                    cmask |= 1u << (3 * s);
                }
                if (x1 >= PCUT_BITS) {
                    atomicAdd(&hist[(x1 >> 21) - BIN0], 1u);
                    cmask |= 1u << (3 * s + 1);
                }
                if (have2) {
                    float p2 = e2[s] * ri;
                    u32 x2 = __float_as_uint(p2);
                    if (x2 >= PCUT_BITS) {
                        atomicAdd(&hist[(x2 >> 21) - BIN0], 1u);
                        cmask |= 1u << (3 * s + 2);
                    }
                }
                if (l == 0) { rowmax[RM(r)] = m[s]; rinv[RM(r)] = ri; }
            }
        }
    }
    __syncthreads();

    // ---- Phase 3: threshold bin T — single-wave 64-bin suffix scan ----
    if (tid < 64) {
        u32 suf = hist[tid];
        #pragma unroll
        for (int off = 1; off < 64; off <<= 1) {
            u32 o = (u32)__shfl_down((int)suf, off, 64);
            suf += (tid + off < 64) ? o : 0;
        }
        u32 nxt = (u32)__shfl_down((int)suf, 1, 64);
        if (tid == 63) nxt = 0;
        if (suf >= (u32)K_ && nxt < (u32)K_) *sT = BIN0 + tid;
    }
    __syncthreads();   // T visible; hist dead (cand may alias)
    const int T = *sT;

    // ---- Phase 4: candidate scan driven by the mask — recompute prob for
    // the ~2 masked elements per thread, bit-identical to phase 1
    // (same expf(v-m)*ri with the exact same m, ri values from LDS).
    // rowmax/rinv reads use padded index -> no same-bank serialization. ----
    u32 mk = cmask;
    while (mk) {
        int bpos = (int)__builtin_ctz(mk);
        mk &= mk - 1;
        int s = (bpos * 171) >> 9;       // floor(bpos/3) for bpos in [0,30)
        int c = bpos - 3 * s;
        int r = g + 32 * s;
        int col = l + 32 * c;
        int i = r * C_ + col;
        float p = expf(lg[i] - rowmax[RM(r)]) * rinv[RM(r)];
        u32 xb = __float_as_uint(p);
        if ((int)(xb >> 21) >= T) {
            u32 pos = atomicAdd(s_cnt, 1u);
            if (pos < (u32)CAP)
                cand[pos] = ((u64)xb << 32) | (u32)(~i);
        }
    }
    __syncthreads();
    const int ncand = (int)*s_cnt;

    if (ncand <= CAP) {
        // ---- Phase 5: parallel rank-by-count top-K select. Thread e ranks
        // cand[e] by scanning all candidates; every lane reads the SAME
        // address per iteration -> LDS broadcast, conflict-free, pipelined.
        // Keys unique (index in low bits) -> ranks are a permutation; rank
        // order == descending sort order of the old bitonic. Uses up to 16
        // waves instead of 1, no dependent cross-lane chains, no barriers. ----
        if (tid < ncand) {
            u64 mykey = cand[tid];
            int rank = 0;
            int f = 0;
            for (; f + 4 <= ncand; f += 4) {
                u64 k0 = cand[f], k1 = cand[f + 1];
                u64 k2 = cand[f + 2], k3 = cand[f + 3];
                rank += (k0 > mykey) ? 1 : 0;
                rank += (k1 > mykey) ? 1 : 0;
                rank += (k2 > mykey) ? 1 : 0;
                rank += (k3 > mykey) ? 1 : 0;
            }
            for (; f < ncand; ++f) rank += (cand[f] > mykey) ? 1 : 0;
            if (rank < K_) {
                sel_val[rank] = __uint_as_float((u32)(mykey >> 32));
                sel_idx[rank] = ~(u32)mykey;
            }
        }
    } else {
        // ---- Phase 5c (near-dead): 100-round argmax with strict-less chaining ----
        if (tid == 0) *s_prev = ~0ull;
        __syncthreads();
        for (int r = 0; r < K_; r++) {
            u64 prev = *s_prev;
            u64 local = 0;
            for (int i = tid; i < QC_; i += NT) {
                int q = i / C_;
                float p = expf(lg[i] - rowmax[RM(q)]) * rinv[RM(q)];
                u64 key = ((u64)__float_as_uint(p) << 32) | (u32)(~i);
                if (key < prev && key > local) local = key;
            }
            for (int off = 32; off > 0; off >>= 1) {
                u64 o = shfl_xor_u64(local, off);
                if (o > local) local = o;
            }
            if ((tid & 63) == 0) wred[tid >> 6] = local;
            __syncthreads();
            if (tid == 0) {
                u64 m = wred[0];
                for (int wv = 1; wv < 16; wv++) if (wred[wv] > m) m = wred[wv];
                *s_prev = m;
                u32 idx = ~(u32)m;
                if (idx >= (u32)QC_) idx = 0;
                sel_val[r] = __uint_as_float((u32)(m >> 32));
                sel_idx[r] = idx;
            }
            __syncthreads();
        }
    }
    __syncthreads();   // sel_* visible; hist/cand/rowstats dead

    // ---- Fused phase 5.5+6+6.5: threads 0-799 compute hoi scores row-per-
    // 8-lane-cluster with in-register row max; threads 800-999 do box
    // gather+scale+areas; 1000-1003 zero keep_bits. ----
    if (tid < 800) {
        int c = tid >> 3, j = tid & 7;
        u32 idx = sel_idx[c];
        int q = (int)idx / C_, lab = (int)idx - q * C_;
        const float* vrow = verb_logits + ((size_t)b * Q_ + q) * V_;
        float sv = sel_val[c];
        float xv[15], cv[15];
        #pragma unroll
        for (int k = 0; k < 15; ++k) {
            int v = j + 8 * k;
            int vc = v < V_ ? v : V_ - 1;
            xv[k] = vrow[vc];
            cv[k] = cm[vc * C_ + lab];
        }
        float m = 0.f;   // hvals >= 0
        #pragma unroll
        for (int k = 0; k < 15; ++k) {
            int v = j + 8 * k;
            if (v < V_) {
                float hv = (1.f / (1.f + expf(-xv[k]))) * sv * cv[k];
                hs[c * V_ + v] = hv;
                m = fmaxf(m, hv);
            }
        }
        m = fmaxf(m, bfly4(m));
        m = fmaxf(m, bfly2(m));
        m = fmaxf(m, bfly1(m));
        if (j == 0) { maxbits[c] = __float_as_uint(m); lab8[c] = (u8)lab; }
    } else if (tid < 900) {
        int t = tid - 800;
        int idx = (int)sel_idx[t];
        int q = idx / C_;
        float iw = (float)tsizes[b * 2 + 1];
        float ih = (float)tsizes[b * 2 + 0];
        float4 sb = ((const float4*)sub_boxes_in)[(size_t)b * Q_ + q];
        float x1 = (sb.x - 0.5f * sb.z) * iw, y1 = (sb.y - 0.5f * sb.w) * ih;
        float x2 = (sb.x + 0.5f * sb.z) * iw, y2 = (sb.y + 0.5f * sb.w) * ih;
        bsub[t][0] = x1; bsub[t][1] = y1; bsub[t][2] = x2; bsub[t][3] = y2;
        asub[t] = (x2 - x1 + 1.f) * (y2 - y1 + 1.f);
        supcol[t][0] = 0; supcol[t][1] = 0; supcol[t][2] = 0; supcol[t][3] = 0;
    } else if (tid < 1000) {
        int t = tid - 900;
        int idx = (int)sel_idx[t];
        int q = idx / C_;
        float iw = (float)tsizes[b * 2 + 1];
        float ih = (float)tsizes[b * 2 + 0];
        float4 ob = ((const float4*)obj_boxes_in)[(size_t)b * Q_ + q];
        float x1 = (ob.x - 0.5f * ob.z) * iw, y1 = (ob.y - 0.5f * ob.w) * ih;
        float x2 = (ob.x + 0.5f * ob.z) * iw, y2 = (ob.y + 0.5f * ob.w) * ih;
        bobj[t][0] = x1; bobj[t][1] = y1; bobj[t][2] = x2; bobj[t][3] = y2;
        aobj[t] = (x2 - x1 + 1.f) * (y2 - y1 + 1.f);
    } else if (tid < 1004) {
        keep_bits[tid - 1000] = 0;
    }
    __syncthreads();

    // ---- Phase 7: stable descending rank, 8 lanes/row, exact int sums ----
    if (tid < 800) {
        int r = tid >> 3, j = tid & 7;
        u64 kr = ((u64)maxbits[r] << 32) | (u32)(~r);
        int rank = 0;
        for (int k = 0; k < 13; k++) {
            int jj = j * 13 + k;
            if (jj < K_) {
                u64 kj = ((u64)maxbits[jj] << 32) | (u32)(~jj);
                rank += (kj > kr) ? 1 : 0;
            }
        }
        rank += ibfly4(rank);
        rank += ibfly2(rank);
        rank += ibfly1(rank);
        if (j == 0) order8[rank] = (u8)r;
    }
    __syncthreads();

    // ---- Early output writes: o1..o4 depend only on sel/boxes (NOT keep).
    // Issue them here so the global stores drain underneath phases 8a/8b. ----
    float* o0 = out;                                   // final_scores B,K,V
    float* o1 = out + (size_t)B_ * KV_;                // topk_values  B,K
    float* o2 = o1 + (size_t)B_ * K_;                  // obj_labels   B,K
    float* o3 = o2 + (size_t)B_ * K_;                  // sub_boxes    B,K,4
    float* o4 = o3 + (size_t)B_ * K_ * 4;              // obj_boxes    B,K,4
    float* o5 = o4 + (size_t)B_ * K_ * 4;              // keep         B,K

    if (tid < K_) {
        o1[(size_t)b * K_ + tid] = sel_val[tid];
        o2[(size_t)b * K_ + tid] = (float)(sel_idx[tid] % (u32)C_);
    }
    if (tid >= 128 && tid < 128 + K_ * 4) {
        int t = tid - 128;
        int r = t >> 2, k = t & 3;
        o3[((size_t)b * K_) * 4 + t] = bsub[r][k];
        o4[((size_t)b * K_) * 4 + t] = bobj[r][k];
    }

    // ---- Phase 8a: 100x100 suppression bitmatrix, COLUMN-major in sorted
    // space (b128 box loads + precomputed areas + cached labels) ----
    for (int e = tid; e < K_ * K_; e += NT) {
        int i = e / K_, j = e - i * K_;
        if (j > i) {
            int ri = order8[i], rj = order8[j];
            u32 li = lab8[ri], lj = lab8[rj];
            if (li == lj) {
                float4 s_i = *(const float4*)bsub[ri];
                float4 s_j = *(const float4*)bsub[rj];
                float4 b_i = *(const float4*)bobj[ri];
                float4 b_j = *(const float4*)bobj[rj];
                float o = iou4(s_i, s_j, asub[ri] + asub[rj]) *
                          iou4(b_i, b_j, aobj[ri] + aobj[rj]);
                if (o > 0.5f)
                    atomicOr(&supcol[j][i >> 5], 1u << (i & 31));
            }
        }
    }
    __syncthreads();

    // ---- Phase 8b: greedy scan via ballot — lane j owns column j's
    // suppressed flag; sup_i read from the ballot mask (scalar), updates are
    // 2 VALU ops. No cross-lane shuffles at all. ----
    if (tid < 64) {
        u32 cA[4], cB[4];
        #pragma unroll
        for (int w = 0; w < 4; ++w) cA[w] = supcol[tid][w];
        #pragma unroll
        for (int w = 0; w < 4; ++w) cB[w] = (tid < K_ - 64) ? supcol[tid + 64][w] : 0u;
        bool sA = false, sB = false;
        u32 km[4] = {0, 0, 0, 0};
        #pragma unroll
        for (int i = 0; i < 64; ++i) {
            u64 bal = __ballot(sA);
            if (!((bal >> i) & 1)) {          // uniform branch
                km[i >> 5] |= 1u << (i & 31);
                sA = sA || ((cA[i >> 5] >> (i & 31)) & 1u);
                sB = sB || ((cB[i >> 5] >> (i & 31)) & 1u);
            }
        }
        #pragma unroll
        for (int i = 64; i < K_; ++i) {
            u64 bal = __ballot(sB);
            if (!((bal >> (i - 64)) & 1)) {   // uniform branch
                km[i >> 5] |= 1u << (i & 31);
                sA = sA || ((cA[i >> 5] >> (i & 31)) & 1u);
                sB = sB || ((cB[i >> 5] >> (i & 31)) & 1u);
            }
        }
        if (tid == 0) { skeep[0] = km[0]; skeep[1] = km[1]; skeep[2] = km[2]; skeep[3] = km[3]; }
    }
    __syncthreads();
    if (tid < K_) {
        if ((skeep[tid >> 5] >> (tid & 31)) & 1u) {
            int r = order8[tid];
            atomicOr(&keep_bits[r >> 5], 1u << (r & 31));
        }
    }
    __syncthreads();

    // ---- Phase 9: write remaining outputs (o0 final_scores, o5 keep) ----
    // final_scores as float4: 11700/4 = 2925 vecs, 16B-aligned both sides.
    constexpr int KV4_ = KV_ / 4;
    for (int f4 = tid; f4 < KV4_; f4 += NT) {
        int base = f4 * 4;
        float4 h = *(const float4*)(hs + base);
        int r0 = base / V_, m0 = base - r0 * V_;
        int r1 = r0 + ((m0 + 1) >= V_ ? 1 : 0);
        int r2 = r0 + ((m0 + 2) >= V_ ? 1 : 0);
        int r3 = r0 + ((m0 + 3) >= V_ ? 1 : 0);
        float4 o;
        o.x = ((keep_bits[r0 >> 5] >> (r0 & 31)) & 1u) ? h.x : 0.f;
        o.y = ((keep_bits[r1 >> 5] >> (r1 & 31)) & 1u) ? h.y : 0.f;
        o.z = ((keep_bits[r2 >> 5] >> (r2 & 31)) & 1u) ? h.z : 0.f;
        o.w = ((keep_bits[r3 >> 5] >> (r3 & 31)) & 1u) ? h.w : 0.f;
        *(float4*)(o0 + (size_t)b * KV_ + base) = o;
    }
    if (tid < K_) {
        bool kp = (keep_bits[tid >> 5] >> (tid & 31)) & 1u;
        o5[(size_t)b * K_ + tid] = kp ? 1.f : 0.f;
    }
}

extern "C" void kernel_launch(void* const* d_in, const int* in_sizes, int n_in,
                              void* d_out, int out_size, void* d_ws, size_t ws_size,
                              hipStream_t stream) {
    const float* obj_logits  = (const float*)d_in[0];
    const float* verb_logits = (const float*)d_in[1];
    const float* sub_boxes   = (const float*)d_in[2];
    const float* obj_boxes   = (const float*)d_in[3];
    const float* cm          = (const float*)d_in[4];
    const int*   ts          = (const int*)d_in[5];
    hipLaunchKernelGGL(hoi_kernel, dim3(B_), dim3(NT), 0, stream,
                       obj_logits, verb_logits, sub_boxes, obj_boxes, cm, ts,
                       (float*)d_out);
}

// Round 8
// 127.566 us; speedup vs baseline: 1.0809x; 1.0160x over previous
//
#include <hip/hip_runtime.h>
#include <cmath>

#pragma clang fp contract(off)

#define NT 1024
constexpr int B_ = 256, Q_ = 300, C_ = 81, V_ = 117, K_ = 100;
constexpr int QC_ = Q_ * C_;   // 24300
constexpr int KV_ = K_ * V_;   // 11700
constexpr int CAP = 1024;      // LDS candidate buffer (fallback sort size)
constexpr int CMN = V_ * C_;   // 9477 floats = 37908 B

using u32 = unsigned int;
using u64 = unsigned long long;
using u16 = unsigned short;
using u8  = unsigned char;

// Histogram support: each softmax row max >= 1/81 = 0.0123 (81 values summing
// to 1) -> >= 300 values land in bins >= bin(1/81) = 482, so the top-100
// crossing bin T >= 482. Values below 2^-7 = 0.0078125 (bin 480) can never
// participate. bits >= 0x3C000000 <=> p >= 2^-7 <=> bin >= 480 EXACTLY
// (bin = float-bits >> 21, monotone for positive floats), so a 64-bin
// histogram over [480, 544) gives a bit-identical T.
constexpr u32 PCUT_BITS = 0x3C000000u;
constexpr int BIN0 = 480;
constexpr int NB   = 64;

// ---- LDS layout (lifetime-aliased, hand-packed; 54,848 B) ----
// hs[] is GONE: phase 6 stores scores directly to global o0 (unconditional),
// suppressed rows are re-zeroed after NMS. The freed 46.8 KB hosts a full
// LDS copy of cm (37.9 KB) -> phase 6's column gathers become LDS reads.
constexpr int OFF_CM   = 0;                 // f32[9477] = 37908 B, whole kernel
constexpr int OFF_HIST = 37920;             // u32[64] | cand u64[1024]=8192 | areas (phase>=5.5)
constexpr int OFF_RMAX = OFF_HIST + 8192;   // f32[309] PADDED: idx r+(r>>5) -> bank (g+s)%32
constexpr int OFF_RINV = OFF_RMAX + 1240;   // f32[309] padded likewise
constexpr int OFF_BSUB = OFF_RINV + 1240;   // f32[100][4] (16B aligned)
constexpr int OFF_BOBJ = OFF_BSUB + 1600;   // f32[100][4] | wred u64[16] (fallback 5c)
constexpr int OFF_SUPR = OFF_BOBJ + 1600;   // u32[100][4] col-major supmat | s_prev u64 (5c)
constexpr int OFF_SELV = OFF_SUPR + 1600;   // f32[100]
constexpr int OFF_SELI = OFF_SELV + 400;    // u32[100] flat topk index
constexpr int OFF_MAXB = OFF_SELI + 400;    // u32[100] row-max bits
constexpr int OFF_ORD  = OFF_MAXB + 400;    // u8[100] (pad 104)
constexpr int OFF_LAB  = OFF_ORD + 104;     // u8[100] labels (pad 104)
constexpr int OFF_MISC = OFF_LAB + 104;     // skeep[4], keep_bits[4], s_cnt, sT
constexpr int SMEM_SZ  = OFF_MISC + 48;     // 54,848
static_assert(SMEM_SZ <= 65536, "LDS overflow");
static_assert((OFF_BSUB & 15) == 0 && (OFF_BOBJ & 15) == 0, "b128 align");
static_assert(OFF_HIST >= OFF_CM + CMN * 4, "cm/hist overlap");
static_assert((OFF_HIST & 7) == 0, "cand u64 align");

// padded row-stat index: r + r/32 -> consecutive s-steps (r += 32) move by 33
// slots = different LDS bank each step (fixes the 32-way conflict of r5).
__device__ __forceinline__ int RM(int r) { return r + (r >> 5); }

__device__ __forceinline__ u64 shfl_xor_u64(u64 v, int mask) {
    u32 lo = (u32)v, hi = (u32)(v >> 32);
    lo = (u32)__shfl_xor((int)lo, mask, 64);
    hi = (u32)__shfl_xor((int)hi, mask, 64);
    return ((u64)hi << 32) | lo;
}

// ---- exact butterfly-exchange primitives (same lane pairing as __shfl_xor) --
// xor8 == row_ror:8 (within 16), xor2/xor1 == quad_perm -> VALU DPP (cheap);
// xor16/xor4 stay on ds_swizzle (BitMode (xor<<10)|0x1F).
template <int CTRL>
__device__ __forceinline__ int dpp_i(int x) {
    return __builtin_amdgcn_update_dpp(0, x, CTRL, 0xF, 0xF, true);
}
__device__ __forceinline__ float bfly16(float x){ return __int_as_float(__builtin_amdgcn_ds_swizzle(__float_as_int(x), 0x401F)); }
__device__ __forceinline__ float bfly8 (float x){ return __int_as_float(dpp_i<0x128>(__float_as_int(x))); }
__device__ __forceinline__ float bfly4 (float x){ return __int_as_float(__builtin_amdgcn_ds_swizzle(__float_as_int(x), 0x101F)); }
__device__ __forceinline__ float bfly2 (float x){ return __int_as_float(dpp_i<0x4E>(__float_as_int(x))); }
__device__ __forceinline__ float bfly1 (float x){ return __int_as_float(dpp_i<0xB1>(__float_as_int(x))); }
__device__ __forceinline__ int ibfly4(int x){ return __builtin_amdgcn_ds_swizzle(x, 0x101F); }
__device__ __forceinline__ int ibfly2(int x){ return dpp_i<0x4E>(x); }
__device__ __forceinline__ int ibfly1(int x){ return dpp_i<0xB1>(x); }

// bit-identical to original: inter / ((areaA + areaB) - inter)
__device__ __forceinline__ float iou4(float4 a, float4 b, float areaSum) {
    float xx1 = fmaxf(a.x, b.x);
    float yy1 = fmaxf(a.y, b.y);
    float xx2 = fminf(a.z, b.z);
    float yy2 = fminf(a.w, b.w);
    float w = fmaxf(0.f, xx2 - xx1 + 1.f);
    float h = fmaxf(0.f, yy2 - yy1 + 1.f);
    float inter = w * h;
    return inter / (areaSum - inter);
}

__global__ __launch_bounds__(NT, 4) void hoi_kernel(
    const float* __restrict__ obj_logits,   // B,Q,C
    const float* __restrict__ verb_logits,  // B,Q,V
    const float* __restrict__ sub_boxes_in, // B,Q,4
    const float* __restrict__ obj_boxes_in, // B,Q,4
    const float* __restrict__ cm,           // V,C
    const int*   __restrict__ tsizes,       // B,2 (h,w)
    float* __restrict__ out)
{
    const int b = blockIdx.x;
    const int tid = threadIdx.x;

    __shared__ __align__(16) u8 smem[SMEM_SZ];
    float* cml     = (float*)(smem + OFF_CM);
    u32*   hist    = (u32*)(smem + OFF_HIST);
    u64*   cand    = (u64*)(smem + OFF_HIST);
    float* asub    = (float*)(smem + OFF_HIST);        // phase>=5.5 (hist/cand dead)
    float* aobj    = (float*)(smem + OFF_HIST + 512);  // phase>=5.5
    float* rowmax  = (float*)(smem + OFF_RMAX);
    float* rinv    = (float*)(smem + OFF_RINV);
    float (*bsub)[4]   = (float(*)[4])(smem + OFF_BSUB);
    float (*bobj)[4]   = (float(*)[4])(smem + OFF_BOBJ);
    u32   (*supcol)[4] = (u32(*)[4])(smem + OFF_SUPR); // column-major suppression bits
    float* sel_val = (float*)(smem + OFF_SELV);
    u32*   sel_idx = (u32*)(smem + OFF_SELI);
    u32*   maxbits = (u32*)(smem + OFF_MAXB);
    u8*    order8  = (u8*)(smem + OFF_ORD);
    u8*    lab8    = (u8*)(smem + OFF_LAB);
    u32*   skeep     = (u32*)(smem + OFF_MISC);
    u32*   keep_bits = (u32*)(smem + OFF_MISC + 16);
    u32*   s_cnt     = (u32*)(smem + OFF_MISC + 32);
    int*   sT        = (int*)(smem + OFF_MISC + 36);
    u64*   wred    = (u64*)(smem + OFF_BOBJ);   // 5c scratch
    u64*   s_prev  = (u64*)(smem + OFF_SUPR);   // 5c scratch

    const float* lg = obj_logits + (size_t)b * QC_;

    // ---- Output pointers (concatenated in return order) ----
    float* o0 = out;                                   // final_scores B,K,V
    float* o1 = out + (size_t)B_ * KV_;                // topk_values  B,K
    float* o2 = o1 + (size_t)B_ * K_;                  // obj_labels   B,K
    float* o3 = o2 + (size_t)B_ * K_;                  // sub_boxes    B,K,4
    float* o4 = o3 + (size_t)B_ * K_ * 4;              // obj_boxes    B,K,4
    float* o5 = o4 + (size_t)B_ * K_ * 4;              // keep         B,K

    // ---- Phase 0: zero hist/s_cnt + stage cm into LDS (coalesced float4;
    // cm is L2-hot after the first blocks touch it). Ready long before
    // phase 6 (multiple barriers in between). ----
    if (tid < NB) hist[tid] = 0;
    if (tid == 0) *s_cnt = 0;
    {
        constexpr int CM4 = CMN / 4;          // 2369
        for (int i = tid; i < CM4; i += NT)
            ((float4*)cml)[i] = ((const float4*)cm)[i];
        if (tid == 0) cml[CMN - 1] = cm[CMN - 1];   // 9477 = 2369*4 + 1
    }
    __syncthreads();

    // ---- Phase 1 (fused): softmax + histogram. Cross-barrier state is ONE
    // u32 candidate mask per thread (bit 3s+c = element of row-slot s, col c
    // has p >= 2^-7). Probabilities are NOT kept live (round-4 lesson: the
    // allocator spills them); phase 4 recomputes the ~2 masked elements per
    // thread bit-identically from lg/rowmax/rinv.
    const int g = tid >> 5, l = tid & 31;
    const bool have2 = (l < C_ - 64);   // l < 17
    u32 cmask = 0;
    {
        float v0[10], v1[10], v2[10];
        #pragma unroll
        for (int s = 0; s < 10; ++s) {
            int r = g + 32 * s;
            const float* row = lg + (size_t)((r < Q_ ? r : Q_ - 1) * C_);
            v0[s] = row[l];
            v1[s] = row[l + 32];
            v2[s] = have2 ? row[l + 64] : -INFINITY;
        }
        float m[10];
        #pragma unroll
        for (int s = 0; s < 10; ++s) m[s] = fmaxf(fmaxf(v0[s], v1[s]), v2[s]);
        #pragma unroll
        for (int s = 0; s < 10; ++s) m[s] = fmaxf(m[s], bfly16(m[s]));
        #pragma unroll
        for (int s = 0; s < 10; ++s) m[s] = fmaxf(m[s], bfly8(m[s]));
        #pragma unroll
        for (int s = 0; s < 10; ++s) m[s] = fmaxf(m[s], bfly4(m[s]));
        #pragma unroll
        for (int s = 0; s < 10; ++s) m[s] = fmaxf(m[s], bfly2(m[s]));
        #pragma unroll
        for (int s = 0; s < 10; ++s) m[s] = fmaxf(m[s], bfly1(m[s]));
        float e0[10], e1[10], e2[10], sm[10];
        #pragma unroll
        for (int s = 0; s < 10; ++s) {
            e0[s] = expf(v0[s] - m[s]);
            e1[s] = expf(v1[s] - m[s]);
            e2[s] = have2 ? expf(v2[s] - m[s]) : 0.f;
            sm[s] = e0[s] + e1[s] + e2[s];
        }
        #pragma unroll
        for (int s = 0; s < 10; ++s) sm[s] += bfly16(sm[s]);
        #pragma unroll
        for (int s = 0; s < 10; ++s) sm[s] += bfly8(sm[s]);
        #pragma unroll
        for (int s = 0; s < 10; ++s) sm[s] += bfly4(sm[s]);
        #pragma unroll
        for (int s = 0; s < 10; ++s) sm[s] += bfly2(sm[s]);
        #pragma unroll
        for (int s = 0; s < 10; ++s) sm[s] += bfly1(sm[s]);
        #pragma unroll
        for (int s = 0; s < 10; ++s) {
            int r = g + 32 * s;
            if (r < Q_) {
                float ri = 1.f / sm[s];
                float p0 = e0[s] * ri, p1 = e1[s] * ri;
                u32 x0 = __float_as_uint(p0), x1 = __float_as_uint(p1);
                if (x0 >= PCUT_BITS) {
                    atomicAdd(&hist[(x0 >> 21) - BIN0], 1u);
                    cmask |= 1u << (3 * s);
                }
                if (x1 >= PCUT_BITS) {
                    atomicAdd(&hist[(x1 >> 21) - BIN0], 1u);
                    cmask |= 1u << (3 * s + 1);
                }
                if (have2) {
                    float p2 = e2[s] * ri;
                    u32 x2 = __float_as_uint(p2);
                    if (x2 >= PCUT_BITS) {
                        atomicAdd(&hist[(x2 >> 21) - BIN0], 1u);
                        cmask |= 1u << (3 * s + 2);
                    }
                }
                if (l == 0) { rowmax[RM(r)] = m[s]; rinv[RM(r)] = ri; }
            }
        }
    }
    __syncthreads();

    // ---- Phase 3: threshold bin T — single-wave 64-bin suffix scan ----
    if (tid < 64) {
        u32 suf = hist[tid];
        #pragma unroll
        for (int off = 1; off < 64; off <<= 1) {
            u32 o = (u32)__shfl_down((int)suf, off, 64);
            suf += (tid + off < 64) ? o : 0;
        }
        u32 nxt = (u32)__shfl_down((int)suf, 1, 64);
        if (tid == 63) nxt = 0;
        if (suf >= (u32)K_ && nxt < (u32)K_) *sT = BIN0 + tid;
    }
    __syncthreads();   // T visible; hist dead (cand may alias)
    const int T = *sT;

    // ---- Phase 4: candidate scan driven by the mask — recompute prob for
    // the ~2 masked elements per thread, bit-identical to phase 1
    // (same expf(v-m)*ri with the exact same m, ri values from LDS).
    // rowmax/rinv reads use padded index -> no same-bank serialization. ----
    u32 mk = cmask;
    while (mk) {
        int bpos = (int)__builtin_ctz(mk);
        mk &= mk - 1;
        int s = (bpos * 171) >> 9;       // floor(bpos/3) for bpos in [0,30)
        int c = bpos - 3 * s;
        int r = g + 32 * s;
        int col = l + 32 * c;
        int i = r * C_ + col;
        float p = expf(lg[i] - rowmax[RM(r)]) * rinv[RM(r)];
        u32 xb = __float_as_uint(p);
        if ((int)(xb >> 21) >= T) {
            u32 pos = atomicAdd(s_cnt, 1u);
            if (pos < (u32)CAP)
                cand[pos] = ((u64)xb << 32) | (u32)(~i);
        }
    }
    __syncthreads();
    const int ncand = (int)*s_cnt;

    if (ncand <= CAP) {
        // ---- Phase 5: parallel rank-by-count top-K select. Thread e ranks
        // cand[e] by scanning all candidates; every lane reads the SAME
        // address per iteration -> LDS broadcast, conflict-free, pipelined.
        // Keys unique (index in low bits) -> ranks are a permutation. ----
        if (tid < ncand) {
            u64 mykey = cand[tid];
            int rank = 0;
            int f = 0;
            for (; f + 4 <= ncand; f += 4) {
                u64 k0 = cand[f], k1 = cand[f + 1];
                u64 k2 = cand[f + 2], k3 = cand[f + 3];
                rank += (k0 > mykey) ? 1 : 0;
                rank += (k1 > mykey) ? 1 : 0;
                rank += (k2 > mykey) ? 1 : 0;
                rank += (k3 > mykey) ? 1 : 0;
            }
            for (; f < ncand; ++f) rank += (cand[f] > mykey) ? 1 : 0;
            if (rank < K_) {
                sel_val[rank] = __uint_as_float((u32)(mykey >> 32));
                sel_idx[rank] = ~(u32)mykey;
            }
        }
    } else {
        // ---- Phase 5c (near-dead): 100-round argmax with strict-less chaining ----
        if (tid == 0) *s_prev = ~0ull;
        __syncthreads();
        for (int r = 0; r < K_; r++) {
            u64 prev = *s_prev;
            u64 local = 0;
            for (int i = tid; i < QC_; i += NT) {
                int q = i / C_;
                float p = expf(lg[i] - rowmax[RM(q)]) * rinv[RM(q)];
                u64 key = ((u64)__float_as_uint(p) << 32) | (u32)(~i);
                if (key < prev && key > local) local = key;
            }
            for (int off = 32; off > 0; off >>= 1) {
                u64 o = shfl_xor_u64(local, off);
                if (o > local) local = o;
            }
            if ((tid & 63) == 0) wred[tid >> 6] = local;
            __syncthreads();
            if (tid == 0) {
                u64 m = wred[0];
                for (int wv = 1; wv < 16; wv++) if (wred[wv] > m) m = wred[wv];
                *s_prev = m;
                u32 idx = ~(u32)m;
                if (idx >= (u32)QC_) idx = 0;
                sel_val[r] = __uint_as_float((u32)(m >> 32));
                sel_idx[r] = idx;
            }
            __syncthreads();
        }
    }
    __syncthreads();   // sel_* visible; hist/cand/rowstats dead

    // ---- Fused phase 5.5+6+6.5: threads 0-799 compute hoi scores row-per-
    // 8-lane-cluster, cm from LDS, row max in registers, scores stored
    // DIRECTLY to o0 (unconditional; suppressed rows re-zeroed after NMS).
    // Threads 800-999: box gather+scale+areas; 1000-1003: zero keep_bits. ----
    if (tid < 800) {
        int c = tid >> 3, j = tid & 7;
        u32 idx = sel_idx[c];
        int q = (int)idx / C_, lab = (int)idx - q * C_;
        const float* vrow = verb_logits + ((size_t)b * Q_ + q) * V_;
        float* orow = o0 + (size_t)b * KV_ + c * V_;
        float sv = sel_val[c];
        float m = 0.f;   // hvals >= 0
        #pragma unroll
        for (int k = 0; k < 15; ++k) {
            int v = j + 8 * k;
            if (v < V_) {
                float x = vrow[v];
                float cv = cml[v * C_ + lab];
                float hv = (1.f / (1.f + expf(-x))) * sv * cv;
                orow[v] = hv;
                m = fmaxf(m, hv);
            }
        }
        m = fmaxf(m, bfly4(m));
        m = fmaxf(m, bfly2(m));
        m = fmaxf(m, bfly1(m));
        if (j == 0) { maxbits[c] = __float_as_uint(m); lab8[c] = (u8)lab; }
    } else if (tid < 900) {
        int t = tid - 800;
        int idx = (int)sel_idx[t];
        int q = idx / C_;
        float iw = (float)tsizes[b * 2 + 1];
        float ih = (float)tsizes[b * 2 + 0];
        float4 sb = ((const float4*)sub_boxes_in)[(size_t)b * Q_ + q];
        float x1 = (sb.x - 0.5f * sb.z) * iw, y1 = (sb.y - 0.5f * sb.w) * ih;
        float x2 = (sb.x + 0.5f * sb.z) * iw, y2 = (sb.y + 0.5f * sb.w) * ih;
        bsub[t][0] = x1; bsub[t][1] = y1; bsub[t][2] = x2; bsub[t][3] = y2;
        asub[t] = (x2 - x1 + 1.f) * (y2 - y1 + 1.f);
        supcol[t][0] = 0; supcol[t][1] = 0; supcol[t][2] = 0; supcol[t][3] = 0;
    } else if (tid < 1000) {
        int t = tid - 900;
        int idx = (int)sel_idx[t];
        int q = idx / C_;
        float iw = (float)tsizes[b * 2 + 1];
        float ih = (float)tsizes[b * 2 + 0];
        float4 ob = ((const float4*)obj_boxes_in)[(size_t)b * Q_ + q];
        float x1 = (ob.x - 0.5f * ob.z) * iw, y1 = (ob.y - 0.5f * ob.w) * ih;
        float x2 = (ob.x + 0.5f * ob.z) * iw, y2 = (ob.y + 0.5f * ob.w) * ih;
        bobj[t][0] = x1; bobj[t][1] = y1; bobj[t][2] = x2; bobj[t][3] = y2;
        aobj[t] = (x2 - x1 + 1.f) * (y2 - y1 + 1.f);
    } else if (tid < 1004) {
        keep_bits[tid - 1000] = 0;
    }
    __syncthreads();   // drains vmcnt(0) per wave: all o0 stores complete

    // ---- Phase 7: stable descending rank, 8 lanes/row, exact int sums ----
    if (tid < 800) {
        int r = tid >> 3, j = tid & 7;
        u64 kr = ((u64)maxbits[r] << 32) | (u32)(~r);
        int rank = 0;
        for (int k = 0; k < 13; k++) {
            int jj = j * 13 + k;
            if (jj < K_) {
                u64 kj = ((u64)maxbits[jj] << 32) | (u32)(~jj);
                rank += (kj > kr) ? 1 : 0;
            }
        }
        rank += ibfly4(rank);
        rank += ibfly2(rank);
        rank += ibfly1(rank);
        if (j == 0) order8[rank] = (u8)r;
    }
    __syncthreads();

    // ---- Early output writes: o1..o4 depend only on sel/boxes (NOT keep).
    // Issue them here so the global stores drain underneath phases 8a/8b. ----
    if (tid < K_) {
        o1[(size_t)b * K_ + tid] = sel_val[tid];
        o2[(size_t)b * K_ + tid] = (float)(sel_idx[tid] % (u32)C_);
    }
    if (tid >= 128 && tid < 128 + K_ * 4) {
        int t = tid - 128;
        int r = t >> 2, k = t & 3;
        o3[((size_t)b * K_) * 4 + t] = bsub[r][k];
        o4[((size_t)b * K_) * 4 + t] = bobj[r][k];
    }

    // ---- Phase 8a: 100x100 suppression bitmatrix, COLUMN-major in sorted
    // space (b128 box loads + precomputed areas + cached labels) ----
    for (int e = tid; e < K_ * K_; e += NT) {
        int i = e / K_, j = e - i * K_;
        if (j > i) {
            int ri = order8[i], rj = order8[j];
            u32 li = lab8[ri], lj = lab8[rj];
            if (li == lj) {
                float4 s_i = *(const float4*)bsub[ri];
                float4 s_j = *(const float4*)bsub[rj];
                float4 b_i = *(const float4*)bobj[ri];
                float4 b_j = *(const float4*)bobj[rj];
                float o = iou4(s_i, s_j, asub[ri] + asub[rj]) *
                          iou4(b_i, b_j, aobj[ri] + aobj[rj]);
                if (o > 0.5f)
                    atomicOr(&supcol[j][i >> 5], 1u << (i & 31));
            }
        }
    }
    __syncthreads();

    // ---- Phase 8b: greedy scan via ballot — lane j owns column j's
    // suppressed flag; sup_i read from the ballot mask (scalar), updates are
    // 2 VALU ops. No cross-lane shuffles at all. ----
    if (tid < 64) {
        u32 cA[4], cB[4];
        #pragma unroll
        for (int w = 0; w < 4; ++w) cA[w] = supcol[tid][w];
        #pragma unroll
        for (int w = 0; w < 4; ++w) cB[w] = (tid < K_ - 64) ? supcol[tid + 64][w] : 0u;
        bool sA = false, sB = false;
        u32 km[4] = {0, 0, 0, 0};
        #pragma unroll
        for (int i = 0; i < 64; ++i) {
            u64 bal = __ballot(sA);
            if (!((bal >> i) & 1)) {          // uniform branch
                km[i >> 5] |= 1u << (i & 31);
                sA = sA || ((cA[i >> 5] >> (i & 31)) & 1u);
                sB = sB || ((cB[i >> 5] >> (i & 31)) & 1u);
            }
        }
        #pragma unroll
        for (int i = 64; i < K_; ++i) {
            u64 bal = __ballot(sB);
            if (!((bal >> (i - 64)) & 1)) {   // uniform branch
                km[i >> 5] |= 1u << (i & 31);
                sA = sA || ((cA[i >> 5] >> (i & 31)) & 1u);
                sB = sB || ((cB[i >> 5] >> (i & 31)) & 1u);
            }
        }
        if (tid == 0) { skeep[0] = km[0]; skeep[1] = km[1]; skeep[2] = km[2]; skeep[3] = km[3]; }
    }
    __syncthreads();
    if (tid < K_) {
        if ((skeep[tid >> 5] >> (tid & 31)) & 1u) {
            int r = order8[tid];
            atomicOr(&keep_bits[r >> 5], 1u << (r & 31));
        }
    }
    __syncthreads();

    // ---- Phase 9: zero suppressed rows of o0 (few; phase-6 stores already
    // complete — barrier drained vmcnt per wave), write o5 keep flags. ----
    for (int f = tid; f < KV_; f += NT) {
        int r = f / V_;
        if (!((keep_bits[r >> 5] >> (r & 31)) & 1u))
            o0[(size_t)b * KV_ + f] = 0.f;
    }
    if (tid < K_) {
        bool kp = (keep_bits[tid >> 5] >> (tid & 31)) & 1u;
        o5[(size_t)b * K_ + tid] = kp ? 1.f : 0.f;
    }
}

extern "C" void kernel_launch(void* const* d_in, const int* in_sizes, int n_in,
                              void* d_out, int out_size, void* d_ws, size_t ws_size,
                              hipStream_t stream) {
    const float* obj_logits  = (const float*)d_in[0];
    const float* verb_logits = (const float*)d_in[1];
    const float* sub_boxes   = (const float*)d_in[2];
    const float* obj_boxes   = (const float*)d_in[3];
    const float* cm          = (const float*)d_in[4];
    const int*   ts          = (const int*)d_in[5];
    hipLaunchKernelGGL(hoi_kernel, dim3(B_), dim3(NT), 0, stream,
                       obj_logits, verb_logits, sub_boxes, obj_boxes, cm, ts,
                       (float*)d_out);
}